// Round 3
// baseline (65.777 us; speedup 1.0000x reference)
//
#include <hip/hip_runtime.h>
#include <math.h>

#define N_EMB  512
#define N_ELEM (16 * 128 * 128)   // 262144, C==1 so NCHW<->NHWC is identity
#define NBLK   256
#define TPB    256

// LDS bank swizzle: pad one word per 32 -> power-of-2 probe strides of the
// binary search (which otherwise cluster on 1-2 banks, up to 16-way conflict)
// spread across banks. addr(i) = i + i/32.
__device__ __forceinline__ int sw(int i) { return i + (i >> 5); }

// One fused kernel: every block (256 thr) bitonic-sorts the 512 codebook
// scalars in its own LDS (redundant across blocks but wall-clock parallel),
// then branchless binary search per element, float4 I/O, one partial-loss
// store per block.
//
// Barrier economics: with the mapping i = (t/j)*2j + t%j, wave w touches only
// s-chunk [128w, 128w+128) for every stage with j <= 64 (lockstep wave64 +
// compiler-inserted lgkmcnt makes same-wave LDS RAW safe without s_barrier).
// Only j >= 64 stages get __syncthreads(): 6 barriers instead of 45.
__global__ __launch_bounds__(TPB) void vq_kernel(const float* __restrict__ x,
                                                 const float* __restrict__ emb,
                                                 float* __restrict__ out,
                                                 float* __restrict__ partials) {
    __shared__ float s[N_EMB + (N_EMB >> 5) + 2];   // 512 + 16 pad + sentinel
    const int tid = threadIdx.x;
    const int gid = blockIdx.x * TPB + tid;

    // Issue the input load first; vmcnt wait lands at first use (after sort),
    // hiding HBM latency under the sort.
    const float4 xv = reinterpret_cast<const float4*>(x)[gid];

    s[sw(tid)]       = emb[tid];          // EMBED_DIM == 1 -> flat 512 floats
    s[sw(tid + 256)] = emb[tid + 256];
    if (tid == 0) s[sw(N_EMB)] = INFINITY;  // sentinel: pos==511 never picks c1
    __syncthreads();

    for (int k = 2; k <= N_EMB; k <<= 1) {
        for (int j = k >> 1; j > 0; j >>= 1) {
            if (j >= 64) __syncthreads();   // only cross-chunk stages + re-entry
            const int i  = ((tid & ~(j - 1)) << 1) | (tid & (j - 1));
            const int ai = sw(i);
            const int bi = sw(i + j);
            const float a = s[ai];
            const float b = s[bi];
            if ((a > b) == ((i & k) == 0)) { s[ai] = b; s[bi] = a; }
        }
    }
    __syncthreads();

    const float s0 = s[sw(0)];             // broadcast read, shared by 4 searches
    const float xs[4] = {xv.x, xv.y, xv.z, xv.w};
    float q[4];
    float acc = 0.0f;

    #pragma unroll
    for (int e = 0; e < 4; ++e) {
        const float xx = xs[e];
        int pos = 0;                        // largest pos with s[pos] <= xx
        float c0 = s0;                      // tracks s[pos]
        #pragma unroll
        for (int step = 256; step > 0; step >>= 1) {
            const float cand = s[sw(pos + step)];   // pos+step <= 511 always
            if (xx >= cand) { pos += step; c0 = cand; }
        }
        const float c1 = s[sw(pos + 1)];    // INF sentinel at top edge
        const float d0 = xx - c0;           // negative iff xx < s[0]; square fixes
        const float d1 = c1 - xx;
        const float d0s = d0 * d0;
        const float d1s = d1 * d1;
        const bool t0 = (d0s <= d1s);
        q[e] = t0 ? c0 : c1;
        acc += t0 ? d0s : d1s;              // (q - x)^2 for the loss
    }
    reinterpret_cast<float4*>(out)[gid] = make_float4(q[0], q[1], q[2], q[3]);

    // Block partial for the loss: wave shuffle reduce -> LDS across 4 waves ->
    // one plain store per block (no atomics).
    #pragma unroll
    for (int off = 32; off > 0; off >>= 1)
        acc += __shfl_down(acc, off, 64);
    __shared__ float wsum[4];
    if ((tid & 63) == 0) wsum[tid >> 6] = acc;
    __syncthreads();
    if (tid == 0)
        partials[blockIdx.x] = wsum[0] + wsum[1] + wsum[2] + wsum[3];
}

// Tiny second kernel: sum the 256 partials, write the loss scalar directly
// (overwrite -> no zero-init of the poisoned d_out slot needed).
__global__ __launch_bounds__(256) void loss_reduce(const float* __restrict__ partials,
                                                   float* __restrict__ loss_out) {
    float v = partials[threadIdx.x];
    #pragma unroll
    for (int off = 32; off > 0; off >>= 1)
        v += __shfl_down(v, off, 64);
    __shared__ float w4[4];
    if ((threadIdx.x & 63) == 0) w4[threadIdx.x >> 6] = v;
    __syncthreads();
    if (threadIdx.x == 0)
        *loss_out = (w4[0] + w4[1] + w4[2] + w4[3]) * (1.25f / (float)N_ELEM);
}

extern "C" void kernel_launch(void* const* d_in, const int* in_sizes, int n_in,
                              void* d_out, int out_size, void* d_ws, size_t ws_size,
                              hipStream_t stream) {
    const float* x   = (const float*)d_in[0];   // pre_quantized (16,1,128,128)
    const float* emb = (const float*)d_in[1];   // emb_weight (512,1)
    float* out      = (float*)d_out;            // [0..N_ELEM): quantized
    float* loss     = out + N_ELEM;             // [N_ELEM]: scalar loss
    float* partials = (float*)d_ws;             // 256 floats scratch

    vq_kernel<<<NBLK, TPB, 0, stream>>>(x, emb, out, partials);
    loss_reduce<<<1, 256, 0, stream>>>(partials, loss);
}